// Round 1
// baseline (75.900 us; speedup 1.0000x reference)
//
#include <hip/hip_runtime.h>
#include <hip/hip_bf16.h>

#define NDIGIT 10
#define DIM_IN 256
#define DIM_OUT 784
#define BATCH 16384
#define BM 64
#define BN 112                       // 7 x 16, divides 784
#define NBLK (DIM_OUT / BN)          // 7
#define MAX_MTILES (BATCH / BM + NDIGIT)  // 266 worst case

typedef __attribute__((ext_vector_type(4))) float f32x4;
typedef __attribute__((ext_vector_type(8))) short bf16x8;
typedef __attribute__((ext_vector_type(4))) unsigned short u16x4;

// ws int layout:
//  [0..9]   counts
//  [16..26] offsets[11]
//  [32..42] tile_offsets[11]
//  [44]     total_tiles
//  [48..57] cursors
//  [64..]   idx[16384]

__device__ __forceinline__ short f2bf(float f) {
    union { float f; unsigned u; } c; c.f = f;
    unsigned u = c.u;
    u += 0x7fffu + ((u >> 16) & 1u);   // RNE
    return (short)(u >> 16);
}

__global__ void hist_k(const int* __restrict__ label, int* __restrict__ wsi) {
    __shared__ int h[NDIGIT];
    int t = threadIdx.x;
    if (t < NDIGIT) h[t] = 0;
    __syncthreads();
    for (int i = blockIdx.x * blockDim.x + t; i < BATCH; i += gridDim.x * blockDim.x)
        atomicAdd(&h[label[i]], 1);
    __syncthreads();
    if (t < NDIGIT) atomicAdd(&wsi[t], h[t]);
}

__global__ void scan_k(int* __restrict__ wsi) {
    int off = 0, toff = 0;
    for (int g = 0; g < NDIGIT; ++g) {
        wsi[16 + g] = off;
        wsi[32 + g] = toff;
        off  += wsi[g];
        toff += (wsi[g] + BM - 1) / BM;
    }
    wsi[16 + NDIGIT] = off;
    wsi[32 + NDIGIT] = toff;
    wsi[44] = toff;
}

__global__ void scatter_k(const int* __restrict__ label, int* __restrict__ wsi) {
    __shared__ int lc[NDIGIT], lb[NDIGIT];
    int t = threadIdx.x;
    if (t < NDIGIT) lc[t] = 0;
    __syncthreads();
    int i = blockIdx.x * blockDim.x + t;
    int g = 0, r = 0;
    bool valid = (i < BATCH);
    if (valid) { g = label[i]; r = atomicAdd(&lc[g], 1); }
    __syncthreads();
    if (t < NDIGIT) lb[t] = (lc[t] > 0) ? atomicAdd(&wsi[48 + t], lc[t]) : 0;
    __syncthreads();
    if (valid) wsi[64 + wsi[16 + g] + lb[g] + r] = i;
}

__launch_bounds__(256, 2)
__global__ void moe_gemm_k(const float* __restrict__ theta,
                           const float* __restrict__ megaW,
                           const float* __restrict__ megab,
                           const int* __restrict__ wsi,
                           float* __restrict__ out) {
    __shared__ short Bs[BN * DIM_IN];   // 57344 B, XOR-swizzled bf16

    int mt = blockIdx.y;
    int total = wsi[44];
    if (mt >= total) return;            // uniform early-exit, before any barrier

    // map m-tile -> (expert g, local tile)
    int g = 0;
    while (mt >= wsi[32 + g + 1]) ++g;
    int lt    = mt - wsi[32 + g];
    int start = wsi[16 + g];
    int cnt   = wsi[16 + g + 1] - start;
    int row0  = lt * BM;
    int rc    = min(BM, cnt - row0);    // valid rows in this tile (>=1)
    int nb    = blockIdx.x;

    const float* Wg = megaW + ((size_t)g * DIM_OUT + (size_t)nb * BN) * DIM_IN;
    int tid = threadIdx.x;

    // ---- stage W tile (112 x 256 f32 -> bf16 LDS, swizzled) ----
    // 7168 float4 total, 28 per thread, fully coalesced reads
    for (int it = 0; it < 28; ++it) {
        int lin = (it * 256 + tid) * 4;     // element index in tile
        int n = lin >> 8;                   // row (dim_out-local)
        int k = lin & 255;                  // col (dim_in)
        f32x4 v = *(const f32x4*)(Wg + lin);
        u16x4 b;
        b[0] = (unsigned short)f2bf(v[0]);
        b[1] = (unsigned short)f2bf(v[1]);
        b[2] = (unsigned short)f2bf(v[2]);
        b[3] = (unsigned short)f2bf(v[3]);
        int byte = n * (DIM_IN * 2) + k * 2;
        byte ^= (n & 7) << 4;               // bank-conflict swizzle
        *(u16x4*)((char*)Bs + byte) = b;
    }

    // ---- A fragments straight to registers (gathered theta rows) ----
    int wv  = tid >> 6;        // wave 0..3  -> rows [wv*16, wv*16+16)
    int l   = tid & 63;
    int r16 = l & 15;          // A-operand row within 16
    int kg  = l >> 4;          // k-group 0..3 (8 elems each)
    int mloc = wv * 16 + r16;
    const int* idxlist = wsi + 64 + start + row0;
    int asrc = (mloc < rc) ? idxlist[mloc] : idxlist[0];
    const float* Arow = theta + (size_t)asrc * DIM_IN;

    bf16x8 a[8];
#pragma unroll
    for (int ks = 0; ks < 8; ++ks) {
        int k0 = ks * 32 + kg * 8;
        f32x4 v0 = *(const f32x4*)(Arow + k0);
        f32x4 v1 = *(const f32x4*)(Arow + k0 + 4);
        bf16x8 af;
        af[0] = f2bf(v0[0]); af[1] = f2bf(v0[1]);
        af[2] = f2bf(v0[2]); af[3] = f2bf(v0[3]);
        af[4] = f2bf(v1[0]); af[5] = f2bf(v1[1]);
        af[6] = f2bf(v1[2]); af[7] = f2bf(v1[3]);
        a[ks] = af;
    }

    f32x4 acc[NBLK];
#pragma unroll
    for (int ns = 0; ns < NBLK; ++ns) acc[ns] = (f32x4){0.f, 0.f, 0.f, 0.f};

    __syncthreads();

    // ---- MFMA main loop: 8 K-steps x 7 N-subtiles ----
#pragma unroll
    for (int ks = 0; ks < 8; ++ks) {
#pragma unroll
        for (int ns = 0; ns < NBLK; ++ns) {
            int n = ns * 16 + r16;
            int byte = n * (DIM_IN * 2) + (ks * 32 + kg * 8) * 2;
            byte ^= (n & 7) << 4;
            bf16x8 b = *(const bf16x8*)((const char*)Bs + byte);
            acc[ns] = __builtin_amdgcn_mfma_f32_16x16x32_bf16(a[ks], b, acc[ns], 0, 0, 0);
        }
    }

    // ---- epilogue: bias + sigmoid + scattered store ----
    // C/D layout: col = lane&15, row = (lane>>4)*4 + j
    const float* bg = megab + (size_t)g * DIM_OUT + (size_t)nb * BN;
    int rbase = wv * 16 + kg * 4;
#pragma unroll
    for (int ns = 0; ns < NBLK; ++ns) {
        int nloc = ns * 16 + r16;
        float bias = bg[nloc];
#pragma unroll
        for (int j = 0; j < 4; ++j) {
            int rl = rbase + j;
            if (rl < rc) {
                int row = idxlist[rl];
                float x = acc[ns][j] + bias;
                out[(size_t)row * DIM_OUT + nb * BN + nloc] = 1.0f / (1.0f + __expf(-x));
            }
        }
    }
}

extern "C" void kernel_launch(void* const* d_in, const int* in_sizes, int n_in,
                              void* d_out, int out_size, void* d_ws, size_t ws_size,
                              hipStream_t stream) {
    const float* theta = (const float*)d_in[0];
    const int*   label = (const int*)d_in[1];
    const float* megaW = (const float*)d_in[2];
    const float* megab = (const float*)d_in[3];
    float* out = (float*)d_out;
    int* wsi = (int*)d_ws;

    hipMemsetAsync(d_ws, 0, 64 * sizeof(int), stream);   // counts + cursors + scalars
    hist_k   <<<32, 256, 0, stream>>>(label, wsi);
    scan_k   <<<1, 1, 0, stream>>>(wsi);
    scatter_k<<<(BATCH + 255) / 256, 256, 0, stream>>>(label, wsi);
    moe_gemm_k<<<dim3(NBLK, MAX_MTILES), 256, 0, stream>>>(theta, megaW, megab, wsi, out);
}

// Round 2
// 72.900 us; speedup vs baseline: 1.0412x; 1.0412x over previous
//
#include <hip/hip_runtime.h>
#include <hip/hip_bf16.h>

#define NDIGIT 10
#define DIM_IN 256
#define DIM_OUT 784
#define BATCH 16384
#define BM 64
#define BN 112                        // 7 x 16, divides 784
#define NBLK (DIM_OUT / BN)           // 7
#define MAX_MTILES (BATCH / BM + NDIGIT)   // 266 worst case
#define GEMM_BLOCKS (2 * MAX_MTILES)       // 532

// ---- new ws layout (ints) ----
//  [0..10]   bucket offsets[11]
//  [12..22]  tile offsets[11]
//  [24]      total_tiles
//  [64 + j*16 + g]  per-hist-block partial counts (j<32, g<10)
//  [1024..17407]    idx[16384]
//  byte 69632..     W in bf16 (2,007,040 shorts = 4,014,080 B)
#define WS_IDX 1024
#define WS_WBF_BYTES 69632
#define WS_NEEDED (WS_WBF_BYTES + 2007040 * 2)

typedef __attribute__((ext_vector_type(4))) float f32x4;
typedef __attribute__((ext_vector_type(8))) short bf16x8;
typedef __attribute__((ext_vector_type(4))) unsigned short u16x4;

__device__ __forceinline__ short f2bf(float f) {
    union { float f; unsigned u; } c; c.f = f;
    unsigned u = c.u;
    u += 0x7fffu + ((u >> 16) & 1u);   // RNE
    return (short)(u >> 16);
}

__device__ __forceinline__ void gload16(const void* gp, void* lp) {
    __builtin_amdgcn_global_load_lds(
        (const __attribute__((address_space(1))) void*)gp,
        (__attribute__((address_space(3))) void*)lp, 16, 0, 0);
}

// =====================  NEW PATH  =====================

// blocks [0,980): convert megaW f32 -> bf16 into ws
// blocks [980,1012): per-512-row label histograms -> ws[64 + j*16 + g]
__global__ void prep_k(const float* __restrict__ megaW,
                       const int* __restrict__ label,
                       int* __restrict__ wsi,
                       short* __restrict__ wbf) {
    int b = blockIdx.x, t = threadIdx.x;
    if (b < 980) {
        int base = b * 2048 + t * 8;       // 980*2048 = 2,007,040 exact
        f32x4 v0 = *(const f32x4*)(megaW + base);
        f32x4 v1 = *(const f32x4*)(megaW + base + 4);
        bf16x8 o;
        o[0] = f2bf(v0[0]); o[1] = f2bf(v0[1]); o[2] = f2bf(v0[2]); o[3] = f2bf(v0[3]);
        o[4] = f2bf(v1[0]); o[5] = f2bf(v1[1]); o[6] = f2bf(v1[2]); o[7] = f2bf(v1[3]);
        *(bf16x8*)(wbf + base) = o;
    } else {
        __shared__ int h[NDIGIT];
        int j = b - 980;
        if (t < NDIGIT) h[t] = 0;
        __syncthreads();
        int i0 = j * 512;
        atomicAdd(&h[label[i0 + t]], 1);
        atomicAdd(&h[label[i0 + 256 + t]], 1);
        __syncthreads();
        if (t < NDIGIT) wsi[64 + j * 16 + t] = h[t];
    }
}

// 32 blocks x 512 threads; each block owns rows [j*512, j*512+512)
__global__ void scatter2_k(const int* __restrict__ label, int* __restrict__ wsi) {
    __shared__ int tot[NDIGIT], bef[NDIGIT], base[NDIGIT + 1], cur[NDIGIT];
    int j = blockIdx.x, t = threadIdx.x;
    if (t < NDIGIT) {
        int s = 0, sb = 0;
        for (int jj = 0; jj < 32; ++jj) {
            int v = wsi[64 + jj * 16 + t];
            s += v;
            if (jj < j) sb += v;
        }
        tot[t] = s; bef[t] = sb;
    }
    __syncthreads();
    if (t == 0) {
        int off = 0;
        for (int g = 0; g < NDIGIT; ++g) { base[g] = off; off += tot[g]; }
        base[NDIGIT] = off;
    }
    __syncthreads();
    if (t < NDIGIT) cur[t] = base[t] + bef[t];
    __syncthreads();
    int i = j * 512 + t;
    int g = label[i];
    int r = atomicAdd(&cur[g], 1);
    wsi[WS_IDX + r] = i;
    if (j == 0 && t == 0) {
        int off = 0, toff = 0;
        for (int g2 = 0; g2 < NDIGIT; ++g2) {
            wsi[g2] = off; wsi[12 + g2] = toff;
            off += tot[g2]; toff += (tot[g2] + BM - 1) / BM;
        }
        wsi[10] = off; wsi[22] = toff; wsi[24] = toff;
    }
}

__launch_bounds__(256, 2)
__global__ void moe_gemm2_k(const float* __restrict__ theta,
                            const float* __restrict__ megab,
                            const int* __restrict__ wsi,
                            const short* __restrict__ wbf,
                            float* __restrict__ out) {
    __shared__ short Bs[BN * DIM_IN];   // 57344 B, XOR-swizzled bf16

    // bijective XCD-chunked swizzle over 532 blocks: both halves of an
    // M-tile (adjacent work ids) land on the same XCD's L2.
    int Bid = blockIdx.x;
    const int q = GEMM_BLOCKS / 8, r = GEMM_BLOCKS % 8;   // 66, 4
    int xcd = Bid & 7, slot = Bid >> 3;
    int w = (xcd < r ? xcd * (q + 1) : r * (q + 1) + (xcd - r) * q) + slot;
    int mt = w >> 1, half = w & 1;

    int total = wsi[24];
    if (mt >= total) return;            // uniform exit before barriers

    int g = 0;
    while (mt >= wsi[12 + g + 1]) ++g;
    int lt    = mt - wsi[12 + g];
    int start = wsi[g];
    int cnt   = wsi[g + 1] - start;
    int row0  = lt * BM;
    int rc    = min(BM, cnt - row0);

    int tid = threadIdx.x;
    int wv = tid >> 6, l = tid & 63, r16 = l & 15, kg = l >> 4;

    const short* Wg = wbf + (size_t)g * DIM_OUT * DIM_IN;
    int nb0 = half ? 4 : 0;
    int nnb = half ? 3 : 4;

    // ---- stage first W tile: async DMA, source pre-swizzled ----
    {
        const short* Wt = Wg + (size_t)nb0 * BN * DIM_IN;
#pragma unroll
        for (int it = 0; it < 14; ++it) {
            int lbyte = (it * 256 + tid) << 4;
            int gbyte = lbyte ^ (((lbyte >> 9) & 7) << 4);
            gload16((const char*)Wt + gbyte, (char*)Bs + lbyte);
        }
    }

    // ---- A fragments (gathered theta rows) once, reused across all nb ----
    const int* idxlist = wsi + WS_IDX + start + row0;
    int mloc = wv * 16 + r16;
    int asrc = (mloc < rc) ? idxlist[mloc] : idxlist[0];
    const float* Arow = theta + (size_t)asrc * DIM_IN;
    bf16x8 a[8];
#pragma unroll
    for (int ks = 0; ks < 8; ++ks) {
        int k0 = ks * 32 + kg * 8;
        f32x4 v0 = *(const f32x4*)(Arow + k0);
        f32x4 v1 = *(const f32x4*)(Arow + k0 + 4);
        bf16x8 af;
        af[0] = f2bf(v0[0]); af[1] = f2bf(v0[1]);
        af[2] = f2bf(v0[2]); af[3] = f2bf(v0[3]);
        af[4] = f2bf(v1[0]); af[5] = f2bf(v1[1]);
        af[6] = f2bf(v1[2]); af[7] = f2bf(v1[3]);
        a[ks] = af;
    }

    const float* bgbase = megab + (size_t)g * DIM_OUT;
    int rbase = wv * 16 + kg * 4;
    int orow[4];
#pragma unroll
    for (int j = 0; j < 4; ++j)
        orow[j] = (rbase + j < rc) ? idxlist[rbase + j] : -1;

    for (int i = 0; i < nnb; ++i) {
        int nb = nb0 + i;
        f32x4 acc[NBLK];
#pragma unroll
        for (int ns = 0; ns < NBLK; ++ns) acc[ns] = (f32x4){0.f, 0.f, 0.f, 0.f};

        __syncthreads();    // staged tile ready (barrier drains vmcnt)

#pragma unroll
        for (int ks = 0; ks < 8; ++ks)
#pragma unroll
            for (int ns = 0; ns < NBLK; ++ns) {
                int n = ns * 16 + r16;
                int byte = (n << 9) + ((ks * 32 + kg * 8) << 1);
                byte ^= (n & 7) << 4;
                bf16x8 bfrag = *(const bf16x8*)((const char*)Bs + byte);
                acc[ns] = __builtin_amdgcn_mfma_f32_16x16x32_bf16(a[ks], bfrag, acc[ns], 0, 0, 0);
            }

        __syncthreads();    // all waves done reading Bs

        if (i + 1 < nnb) {  // issue next stage BEFORE epilogue (overlap)
            const short* Wt = Wg + (size_t)(nb + 1) * BN * DIM_IN;
#pragma unroll
            for (int it = 0; it < 14; ++it) {
                int lbyte = (it * 256 + tid) << 4;
                int gbyte = lbyte ^ (((lbyte >> 9) & 7) << 4);
                gload16((const char*)Wt + gbyte, (char*)Bs + lbyte);
            }
        }

        const float* bg = bgbase + nb * BN;
#pragma unroll
        for (int ns = 0; ns < NBLK; ++ns) {
            int nloc = ns * 16 + r16;
            float bias = bg[nloc];
#pragma unroll
            for (int j = 0; j < 4; ++j) {
                if (orow[j] >= 0) {
                    float x = acc[ns][j] + bias;
                    float y = 1.0f / (1.0f + __expf(-x));
                    __builtin_nontemporal_store(y, out + (size_t)orow[j] * DIM_OUT + nb * BN + nloc);
                }
            }
        }
    }
}

// =====================  FALLBACK PATH (round-1, passing)  =====================

__global__ void hist_k(const int* __restrict__ label, int* __restrict__ wsi) {
    __shared__ int h[NDIGIT];
    int t = threadIdx.x;
    if (t < NDIGIT) h[t] = 0;
    __syncthreads();
    for (int i = blockIdx.x * blockDim.x + t; i < BATCH; i += gridDim.x * blockDim.x)
        atomicAdd(&h[label[i]], 1);
    __syncthreads();
    if (t < NDIGIT) atomicAdd(&wsi[t], h[t]);
}

__global__ void scan_k(int* __restrict__ wsi) {
    int off = 0, toff = 0;
    for (int g = 0; g < NDIGIT; ++g) {
        wsi[16 + g] = off;
        wsi[32 + g] = toff;
        off  += wsi[g];
        toff += (wsi[g] + BM - 1) / BM;
    }
    wsi[16 + NDIGIT] = off;
    wsi[32 + NDIGIT] = toff;
    wsi[44] = toff;
}

__global__ void scatter_k(const int* __restrict__ label, int* __restrict__ wsi) {
    __shared__ int lc[NDIGIT], lb[NDIGIT];
    int t = threadIdx.x;
    if (t < NDIGIT) lc[t] = 0;
    __syncthreads();
    int i = blockIdx.x * blockDim.x + t;
    int g = 0, rr = 0;
    bool valid = (i < BATCH);
    if (valid) { g = label[i]; rr = atomicAdd(&lc[g], 1); }
    __syncthreads();
    if (t < NDIGIT) lb[t] = (lc[t] > 0) ? atomicAdd(&wsi[48 + t], lc[t]) : 0;
    __syncthreads();
    if (valid) wsi[64 + wsi[16 + g] + lb[g] + rr] = i;
}

__launch_bounds__(256, 2)
__global__ void moe_gemm_k(const float* __restrict__ theta,
                           const float* __restrict__ megaW,
                           const float* __restrict__ megab,
                           const int* __restrict__ wsi,
                           float* __restrict__ out) {
    __shared__ short Bs[BN * DIM_IN];
    int mt = blockIdx.y;
    int total = wsi[44];
    if (mt >= total) return;
    int g = 0;
    while (mt >= wsi[32 + g + 1]) ++g;
    int lt    = mt - wsi[32 + g];
    int start = wsi[16 + g];
    int cnt   = wsi[16 + g + 1] - start;
    int row0  = lt * BM;
    int rc    = min(BM, cnt - row0);
    int nb    = blockIdx.x;
    const float* Wg = megaW + ((size_t)g * DIM_OUT + (size_t)nb * BN) * DIM_IN;
    int tid = threadIdx.x;
    for (int it = 0; it < 28; ++it) {
        int lin = (it * 256 + tid) * 4;
        int n = lin >> 8;
        int k = lin & 255;
        f32x4 v = *(const f32x4*)(Wg + lin);
        u16x4 b;
        b[0] = (unsigned short)f2bf(v[0]);
        b[1] = (unsigned short)f2bf(v[1]);
        b[2] = (unsigned short)f2bf(v[2]);
        b[3] = (unsigned short)f2bf(v[3]);
        int byte = n * (DIM_IN * 2) + k * 2;
        byte ^= (n & 7) << 4;
        *(u16x4*)((char*)Bs + byte) = b;
    }
    int wv  = tid >> 6;
    int l   = tid & 63;
    int r16 = l & 15;
    int kg  = l >> 4;
    int mloc = wv * 16 + r16;
    const int* idxlist = wsi + 64 + start + row0;
    int asrc = (mloc < rc) ? idxlist[mloc] : idxlist[0];
    const float* Arow = theta + (size_t)asrc * DIM_IN;
    bf16x8 a[8];
#pragma unroll
    for (int ks = 0; ks < 8; ++ks) {
        int k0 = ks * 32 + kg * 8;
        f32x4 v0 = *(const f32x4*)(Arow + k0);
        f32x4 v1 = *(const f32x4*)(Arow + k0 + 4);
        bf16x8 af;
        af[0] = f2bf(v0[0]); af[1] = f2bf(v0[1]);
        af[2] = f2bf(v0[2]); af[3] = f2bf(v0[3]);
        af[4] = f2bf(v1[0]); af[5] = f2bf(v1[1]);
        af[6] = f2bf(v1[2]); af[7] = f2bf(v1[3]);
        a[ks] = af;
    }
    f32x4 acc[NBLK];
#pragma unroll
    for (int ns = 0; ns < NBLK; ++ns) acc[ns] = (f32x4){0.f, 0.f, 0.f, 0.f};
    __syncthreads();
#pragma unroll
    for (int ks = 0; ks < 8; ++ks) {
#pragma unroll
        for (int ns = 0; ns < NBLK; ++ns) {
            int n = ns * 16 + r16;
            int byte = n * (DIM_IN * 2) + (ks * 32 + kg * 8) * 2;
            byte ^= (n & 7) << 4;
            bf16x8 b = *(const bf16x8*)((const char*)Bs + byte);
            acc[ns] = __builtin_amdgcn_mfma_f32_16x16x32_bf16(a[ks], b, acc[ns], 0, 0, 0);
        }
    }
    const float* bg = megab + (size_t)g * DIM_OUT + (size_t)nb * BN;
    int rbase = wv * 16 + kg * 4;
#pragma unroll
    for (int ns = 0; ns < NBLK; ++ns) {
        int nloc = ns * 16 + r16;
        float bias = bg[nloc];
#pragma unroll
        for (int j = 0; j < 4; ++j) {
            int rl = rbase + j;
            if (rl < rc) {
                int row = idxlist[rl];
                float x = acc[ns][j] + bias;
                out[(size_t)row * DIM_OUT + nb * BN + nloc] = 1.0f / (1.0f + __expf(-x));
            }
        }
    }
}

extern "C" void kernel_launch(void* const* d_in, const int* in_sizes, int n_in,
                              void* d_out, int out_size, void* d_ws, size_t ws_size,
                              hipStream_t stream) {
    const float* theta = (const float*)d_in[0];
    const int*   label = (const int*)d_in[1];
    const float* megaW = (const float*)d_in[2];
    const float* megab = (const float*)d_in[3];
    float* out = (float*)d_out;
    int* wsi = (int*)d_ws;

    if (ws_size >= (size_t)WS_NEEDED) {
        short* wbf = (short*)((char*)d_ws + WS_WBF_BYTES);
        prep_k    <<<1012, 256, 0, stream>>>(megaW, label, wsi, wbf);
        scatter2_k<<<32, 512, 0, stream>>>(label, wsi);
        moe_gemm2_k<<<GEMM_BLOCKS, 256, 0, stream>>>(theta, megab, wsi, wbf, out);
    } else {
        hipMemsetAsync(d_ws, 0, 64 * sizeof(int), stream);
        hist_k   <<<32, 256, 0, stream>>>(label, wsi);
        scan_k   <<<1, 1, 0, stream>>>(wsi);
        scatter_k<<<(BATCH + 255) / 256, 256, 0, stream>>>(label, wsi);
        moe_gemm_k<<<dim3(NBLK, MAX_MTILES), 256, 0, stream>>>(theta, megaW, megab, wsi, out);
    }
}